// Round 1
// baseline (309.379 us; speedup 1.0000x reference)
//
#include <hip/hip_runtime.h>
#include <stdint.h>

#define NN 8192      // nodes per batch
#define EE 8191      // edges per batch
#define AD 256       // ADIM
#define BB 16        // batch

// h buffer: per batch HROWS rows of 264 bf16 (256 data + 8 pad), row r = e + 2.
// Valid rows r=2..8192 (e=0..8190); rows 0,1,8193,8194 are zero pads.
#define HROWS 8196
#define HROWB 528          // bytes per row
#define HROW_U16 264

typedef unsigned short u16;
typedef short bf16x8 __attribute__((ext_vector_type(8)));
typedef float f32x4 __attribute__((ext_vector_type(4)));
typedef u16 u16x8 __attribute__((ext_vector_type(8)));

__device__ __forceinline__ u16 f2bf(float f) {
  unsigned u = __builtin_bit_cast(unsigned, f);
  u = u + 0x7fffu + ((u >> 16) & 1u);   // RNE
  return (u16)(u >> 16);
}

__device__ __forceinline__ void gl_lds16(const char* g, char* l) {
  __builtin_amdgcn_global_load_lds(
      (const __attribute__((address_space(1))) unsigned int*)g,
      (__attribute__((address_space(3))) unsigned int*)l, 16, 0, 0);
}

// ---------------------------------------------------------------------------
// prep_ma: M[tap][o][a] = sum_c K_a[o,c,tap] * W2[c,a]  (bf16, padded layout
// [tap][ac][o][72] with a-chunk ac of 64 + 8 pad), and bk[tap][o] = sum_c
// K_a[o,c,tap]*b2[c].  grid = 1024 (o*4+tap), block = 256 (a).
// ---------------------------------------------------------------------------
__global__ __launch_bounds__(256) void prep_ma(const float* __restrict__ W2,
                                               const float* __restrict__ b2,
                                               const float* __restrict__ K_a,
                                               u16* __restrict__ Ma,
                                               float* __restrict__ bk) {
  __shared__ float ka[256];
  __shared__ float red[256];
  const int tid = threadIdx.x;
  const int o = blockIdx.x >> 2;
  const int tap = blockIdx.x & 3;
  ka[tid] = K_a[(size_t)((o << 8) + tid) * 4 + tap];
  __syncthreads();
  float acc = 0.f;
  for (int c = 0; c < 256; ++c) acc += ka[c] * W2[(c << 8) + tid];
  red[tid] = ka[tid] * b2[tid];
  __syncthreads();
  if (tid == 0) {
    float s = 0.f;
    for (int c = 0; c < 256; ++c) s += red[c];
    bk[tap * 256 + o] = s;
  }
  const int ac = tid >> 6, j = tid & 63;
  Ma[((size_t)((tap * 4 + ac) * 256 + o)) * 72 + j] = f2bf(acc);
  if (tid < 32)  // zero the 8 pad columns of each of the 4 chunks for this o
    Ma[((size_t)((tap * 4 + (tid >> 3)) * 256 + o)) * 72 + 64 + (tid & 7)] = 0;
}

// ---------------------------------------------------------------------------
// prep_small: block 0 -> Mv[k][o][i] = sum_c K_v[o,c,k]*W_v[c,i];
// blocks 1..16 -> zero h pad rows {0,1,8193,8194} of batch b-1;
// block 17 -> bias_all[o] = b_a[o] + sum_k bk[k][o].   grid = 18, block = 256.
// ---------------------------------------------------------------------------
__global__ __launch_bounds__(256) void prep_small(const float* __restrict__ W_v,
                                                  const float* __restrict__ K_v,
                                                  const float* __restrict__ b_a,
                                                  const float* __restrict__ bk,
                                                  float* __restrict__ Mv,
                                                  float* __restrict__ bias_all,
                                                  u16* __restrict__ hbuf) {
  const int tid = threadIdx.x, bid = blockIdx.x;
  if (bid == 0) {
    for (int idx = tid; idx < 2048; idx += 256) {
      const int k = idx >> 9, rem = idx & 511, o = rem >> 2, i = rem & 3;
      float acc = 0.f;
      for (int c = 0; c < 128; ++c)
        acc += K_v[(size_t)((o << 7) + c) * 4 + k] * W_v[(c << 2) + i];
      Mv[idx] = acc;   // layout [k][o][i], flat == idx
    }
  } else if (bid <= 16) {
    const int b = bid - 1;
    const int rows[4] = {0, 1, 8193, 8194};
    for (int idx = tid; idx < 4 * HROW_U16; idx += 256) {
      const int rs = idx / HROW_U16, c = idx - rs * HROW_U16;
      hbuf[((size_t)b * HROWS + rows[rs]) * HROW_U16 + c] = 0;
    }
  } else {
    bias_all[tid] = b_a[tid] + bk[tid] + bk[256 + tid] + bk[512 + tid] + bk[768 + tid];
  }
}

// ---------------------------------------------------------------------------
// h_gen: h[e,a] = LeakyReLU(b1[a] + sum_f norms[e,f]*W1[a,f]) -> bf16 row e+2.
// grid = 16*128 (64 edges/block), block = 256 (quad per edge: 4 a-ranges).
// ---------------------------------------------------------------------------
__global__ __launch_bounds__(256) void h_gen(const float* __restrict__ p0,
                                             const float* __restrict__ p1,
                                             const float* __restrict__ W1,
                                             const float* __restrict__ b1,
                                             u16* __restrict__ hbuf) {
  __shared__ float W1s[1024];
  __shared__ float b1s[256];
  __shared__ float nrm[64][4];
  const int tid = threadIdx.x;
  const int b = blockIdx.x >> 7;
  const int e0 = (blockIdx.x & 127) * 64;
  for (int i = tid; i < 1024; i += 256) W1s[i] = W1[i];
  b1s[tid] = b1[tid];
  const int le = tid >> 2, i = tid & 3;
  const int e = e0 + le;
  if (e < EE) {
    const size_t base = (size_t)b * NN * 3;
    const float* P0 = p0 + base;
    const float* P1 = p1 + base;
    // vec 0: p0[e+1]-p0[e]; 1: p1[e+1]-p1[e]; 2: p1[e]-p0[e+1]; 3: p1[e+1]-p0[e]
    const float* hi = (i == 0) ? P0 + (size_t)(e + 1) * 3
                    : (i == 1) ? P1 + (size_t)(e + 1) * 3
                    : (i == 2) ? P1 + (size_t)e * 3
                               : P1 + (size_t)(e + 1) * 3;
    const float* lo = (i == 0) ? P0 + (size_t)e * 3
                    : (i == 1) ? P1 + (size_t)e * 3
                    : (i == 2) ? P0 + (size_t)(e + 1) * 3
                               : P0 + (size_t)e * 3;
    const float dx = hi[0] - lo[0], dy = hi[1] - lo[1], dz = hi[2] - lo[2];
    nrm[le][i] = sqrtf(dx * dx + dy * dy + dz * dz);
  }
  __syncthreads();
  if (e < EE) {
    const float n0v = nrm[le][0], n1v = nrm[le][1], n2v = nrm[le][2], n3v = nrm[le][3];
    u16* rp = hbuf + ((size_t)b * HROWS + (e + 2)) * HROW_U16;
    const int a0 = i * 64;
#pragma unroll
    for (int g = 0; g < 8; ++g) {
      u16x8 pack;
#pragma unroll
      for (int j = 0; j < 8; ++j) {
        const int a = a0 + g * 8 + j;
        float v = b1s[a] + n0v * W1s[a * 4] + n1v * W1s[a * 4 + 1] +
                  n2v * W1s[a * 4 + 2] + n3v * W1s[a * 4 + 3];
        v = (v >= 0.f) ? v : 0.2f * v;
        pack[j] = f2bf(v);
      }
      *(u16x8*)(rp + a0 + g * 8) = pack;
    }
  }
}

// ---------------------------------------------------------------------------
// gemm_a: a_out[n,o] = sum_{tap,a} M[tap][o][a]*h[n+tap (row), a] + bias_all[o]
// Tile: 128 nodes x 256 outs, 8 waves (2x4), wave = 64x64, mfma 16x16x32 bf16.
// K = 1024 staged as 16 chunks of (tap, 64-ch), double-buffered LDS.
// grid = 16*64, block = 512.
// ---------------------------------------------------------------------------
__global__ __launch_bounds__(512, 1) void gemm_a(const u16* __restrict__ hbuf,
                                                 const u16* __restrict__ Ma,
                                                 const float* __restrict__ bias_all,
                                                 float* __restrict__ out) {
  __shared__ __align__(16) char hs[131 * HROWB];   // 69,168 B (linear, padded rows)
  __shared__ __align__(16) char bsm[2][36864];     // 73,728 B
  const int tid = threadIdx.x;
  const int lane = tid & 63;
  const int wid = tid >> 6;
  const int wm = wid >> 2, wn = wid & 3;
  const int b = blockIdx.x >> 6;
  const int n0 = (blockIdx.x & 63) * 128;
  const int lhi = lane >> 4;   // 0..3
  const int llo = lane & 15;   // 0..15

  // stage h rows n0..n0+130 (131 rows x 528B), linear
  const char* hsrc = (const char*)hbuf + ((size_t)b * HROWS + n0) * HROWB;
  for (int u = tid; u < 4323; u += 512) gl_lds16(hsrc + (size_t)u * 16, hs + u * 16);
  // stage M chunk 0
  const char* msrc = (const char*)Ma;
  for (int u = tid; u < 2304; u += 512) gl_lds16(msrc + (size_t)u * 16, bsm[0] + u * 16);
  __syncthreads();

  const f32x4 zero = {0.f, 0.f, 0.f, 0.f};
  f32x4 acc[4][4];
#pragma unroll
  for (int m = 0; m < 4; ++m)
#pragma unroll
    for (int nf = 0; nf < 4; ++nf) acc[m][nf] = zero;

  for (int q = 0; q < 16; ++q) {           // q = tap*4 + ac
    if (q < 15) {                          // prefetch next chunk
      const char* src = msrc + (size_t)(q + 1) * 36864;
      char* dst = bsm[(q + 1) & 1];
      for (int u = tid; u < 2304; u += 512) gl_lds16(src + (size_t)u * 16, dst + u * 16);
    }
    const int tap = q >> 2, ac = q & 3;
    const char* bbase = bsm[q & 1];
#pragma unroll
    for (int ks = 0; ks < 2; ++ks) {
      bf16x8 af[4];
      const int cA = ac * 64 + ks * 32 + (lhi << 3);
#pragma unroll
      for (int m = 0; m < 4; ++m) {
        const int rr = wm * 64 + m * 16 + llo + tap;
        af[m] = *(const bf16x8*)(hs + rr * HROWB + cA * 2);
      }
      bf16x8 bfr[4];
      const int cB = ks * 32 + (lhi << 3);
#pragma unroll
      for (int nf = 0; nf < 4; ++nf) {
        const int oo = wn * 64 + nf * 16 + llo;
        bfr[nf] = *(const bf16x8*)(bbase + oo * 144 + cB * 2);
      }
#pragma unroll
      for (int m = 0; m < 4; ++m)
#pragma unroll
        for (int nf = 0; nf < 4; ++nf)
          acc[m][nf] = __builtin_amdgcn_mfma_f32_16x16x32_bf16(af[m], bfr[nf],
                                                               acc[m][nf], 0, 0, 0);
    }
    __syncthreads();
  }

  // epilogue: D element (row = lhi*4+j, col = llo) per 16x16 frag
#pragma unroll
  for (int nf = 0; nf < 4; ++nf) {
    const int oo = wn * 64 + nf * 16 + llo;
    const float bias = bias_all[oo];
#pragma unroll
    for (int m = 0; m < 4; ++m) {
      const int nodeb = n0 + wm * 64 + m * 16 + (lhi << 2);
      float* op = out + ((size_t)b * NN + nodeb) * AD + oo;
#pragma unroll
      for (int j = 0; j < 4; ++j) op[(size_t)j * AD] = acc[m][nf][j] + bias;
    }
  }
}

// ---------------------------------------------------------------------------
// fixup_a: remove bias of conv taps that fall outside the edge range.
// n=0: taps 0,1 invalid; n=1: tap 0; n=N-2: tap 3; n=N-1: taps 2,3.
// ---------------------------------------------------------------------------
__global__ void fixup_a(const float* __restrict__ bk, float* __restrict__ out) {
  const int o = threadIdx.x;
  const int b = blockIdx.x;
  float* base = out + (size_t)b * NN * AD;
  base[o] -= bk[o] + bk[256 + o];
  base[AD + o] -= bk[o];
  base[(size_t)8190 * AD + o] -= bk[768 + o];
  base[(size_t)8191 * AD + o] -= bk[512 + o] + bk[768 + o];
}

// ---------------------------------------------------------------------------
// vec_path: v_out[n,o,d] = sum_{k,i} Mv[k][o][i] * vec(e=n+k-2, i, d)
// 32 nodes/block, 8 threads/node (16 o each), LDS staging for coalesced write.
// grid = 16*256, block = 256.
// ---------------------------------------------------------------------------
__global__ __launch_bounds__(256) void vec_path(const float* __restrict__ p0,
                                                const float* __restrict__ p1,
                                                const float* __restrict__ Mv,
                                                float* __restrict__ out) {
  __shared__ float MvS[2048];
  __shared__ __align__(16) float ob[32 * 384];
  const int tid = threadIdx.x;
  const int b = blockIdx.x >> 8;
  const int n0 = (blockIdx.x & 255) * 32;
  for (int idx = tid; idx < 2048; idx += 256) MvS[idx] = Mv[idx];
  __syncthreads();
  const int nl = tid >> 3, q = tid & 7;
  const int n = n0 + nl;
  const size_t pbase = (size_t)b * NN * 3;
  float s[4][4][3];
#pragma unroll
  for (int k = 0; k < 4; ++k) {
    const int e = n + k - 2;
    if (e >= 0 && e < EE) {
      const float* A0 = p0 + pbase + (size_t)e * 3;
      const float* A1 = p0 + pbase + (size_t)(e + 1) * 3;
      const float* C0 = p1 + pbase + (size_t)e * 3;
      const float* C1 = p1 + pbase + (size_t)(e + 1) * 3;
#pragma unroll
      for (int d = 0; d < 3; ++d) {
        const float a0v = A0[d], a1v = A1[d], c0v = C0[d], c1v = C1[d];
        s[k][0][d] = a1v - a0v;
        s[k][1][d] = c1v - c0v;
        s[k][2][d] = c0v - a1v;
        s[k][3][d] = c1v - a0v;
      }
    } else {
#pragma unroll
      for (int i2 = 0; i2 < 4; ++i2)
#pragma unroll
        for (int d = 0; d < 3; ++d) s[k][i2][d] = 0.f;
    }
  }
  for (int oi = 0; oi < 16; ++oi) {
    const int o = q * 16 + oi;
    float r0 = 0.f, r1 = 0.f, r2 = 0.f;
#pragma unroll
    for (int k = 0; k < 4; ++k) {
      const float* mp = &MvS[((k << 7) + o) << 2];
#pragma unroll
      for (int i2 = 0; i2 < 4; ++i2) {
        const float m = mp[i2];
        r0 += m * s[k][i2][0];
        r1 += m * s[k][i2][1];
        r2 += m * s[k][i2][2];
      }
    }
    ob[nl * 384 + o * 3 + 0] = r0;
    ob[nl * 384 + o * 3 + 1] = r1;
    ob[nl * 384 + o * 3 + 2] = r2;
  }
  __syncthreads();
  float4* dst = (float4*)(out + 33554432ULL + ((size_t)b * NN + n0) * 384);
  const float4* srcv = (const float4*)ob;
  for (int idx = tid; idx < 3072; idx += 256) dst[idx] = srcv[idx];
}

// ---------------------------------------------------------------------------
extern "C" void kernel_launch(void* const* d_in, const int* in_sizes, int n_in,
                              void* d_out, int out_size, void* d_ws, size_t ws_size,
                              hipStream_t stream) {
  const float* pos_0 = (const float*)d_in[0];
  const float* pos_1 = (const float*)d_in[1];
  const float* W_v = (const float*)d_in[2];
  const float* W1 = (const float*)d_in[3];
  const float* b1 = (const float*)d_in[4];
  const float* W2 = (const float*)d_in[5];
  const float* b2 = (const float*)d_in[6];
  const float* K_a = (const float*)d_in[7];
  const float* b_a = (const float*)d_in[8];
  const float* K_v = (const float*)d_in[9];
  float* out = (float*)d_out;
  char* ws = (char*)d_ws;

  const size_t H_BYTES = (size_t)BB * HROWS * HROWB;      // 69,239,808
  const size_t OFF_MA = H_BYTES;
  const size_t MA_BYTES = (size_t)16 * 256 * 72 * 2;      // 589,824
  const size_t OFF_BK = OFF_MA + MA_BYTES;
  const size_t OFF_BIAS = OFF_BK + 4 * 256 * 4;
  const size_t OFF_MV = OFF_BIAS + 256 * 4;

  u16* hbuf = (u16*)(ws);
  u16* Ma = (u16*)(ws + OFF_MA);
  float* bk = (float*)(ws + OFF_BK);
  float* bias_all = (float*)(ws + OFF_BIAS);
  float* Mv = (float*)(ws + OFF_MV);

  prep_ma<<<dim3(1024), dim3(256), 0, stream>>>(W2, b2, K_a, Ma, bk);
  prep_small<<<dim3(18), dim3(256), 0, stream>>>(W_v, K_v, b_a, bk, Mv, bias_all, hbuf);
  h_gen<<<dim3(2048), dim3(256), 0, stream>>>(pos_0, pos_1, W1, b1, hbuf);
  gemm_a<<<dim3(1024), dim3(512), 0, stream>>>(hbuf, Ma, bias_all, out);
  fixup_a<<<dim3(16), dim3(256), 0, stream>>>(bk, out);
  vec_path<<<dim3(4096), dim3(256), 0, stream>>>(pos_0, pos_1, Mv, out);
}

// Round 2
// 259.494 us; speedup vs baseline: 1.1922x; 1.1922x over previous
//
#include <hip/hip_runtime.h>
#include <stdint.h>

#define NN 8192      // nodes per batch
#define EE 8191      // edges per batch
#define AD 256       // ADIM
#define BB 16        // batch

typedef unsigned short u16;
typedef short bf16x8 __attribute__((ext_vector_type(8)));
typedef float f32x4 __attribute__((ext_vector_type(4)));
typedef u16 u16x8 __attribute__((ext_vector_type(8)));

__device__ __forceinline__ u16 f2bf(float f) {
  unsigned u = __builtin_bit_cast(unsigned, f);
  u = u + 0x7fffu + ((u >> 16) & 1u);   // RNE
  return (u16)(u >> 16);
}

// ---------------------------------------------------------------------------
// prep_ma: M[tap][o][a] = sum_c K_a[o,c,tap] * W2[c,a]  (bf16, layout
// [q=tap*4+ac][o][72] with a-chunk ac of 64 + 8 pad), bk[tap][o] = sum_c
// K_a[o,c,tap]*b2[c].  grid = 256 (o), block = 256 (a / c).
// ---------------------------------------------------------------------------
__global__ __launch_bounds__(256) void prep_ma(const float* __restrict__ W2,
                                               const float* __restrict__ b2,
                                               const float* __restrict__ K_a,
                                               u16* __restrict__ Ma,
                                               float* __restrict__ bk) {
  __shared__ float ka[256][4];
  __shared__ float b2s[256];
  const int tid = threadIdx.x;
  const int o = blockIdx.x;
  const float4 kv = ((const float4*)K_a)[(size_t)o * 256 + tid];
  ka[tid][0] = kv.x; ka[tid][1] = kv.y; ka[tid][2] = kv.z; ka[tid][3] = kv.w;
  b2s[tid] = b2[tid];
  __syncthreads();
  float acc[4] = {0.f, 0.f, 0.f, 0.f};
  for (int c = 0; c < 256; ++c) {
    const float w = W2[(c << 8) + tid];
    acc[0] += ka[c][0] * w; acc[1] += ka[c][1] * w;
    acc[2] += ka[c][2] * w; acc[3] += ka[c][3] * w;
  }
  const int ac = tid >> 6, j = tid & 63;
#pragma unroll
  for (int t = 0; t < 4; ++t)
    Ma[((size_t)((t * 4 + ac) * 256 + o)) * 72 + j] = f2bf(acc[t]);
  if (tid < 128) {  // zero the 8 pad cols of each (tap, ac) row for this o
    const int t = tid >> 5, a2 = (tid >> 3) & 3, jj = tid & 7;
    Ma[((size_t)((t * 4 + a2) * 256 + o)) * 72 + 64 + jj] = 0;
  }
  if (tid < 4) {
    float s = 0.f;
    for (int c = 0; c < 256; ++c) s += ka[c][tid] * b2s[c];
    bk[tid * 256 + o] = s;
  }
}

// ---------------------------------------------------------------------------
// prep_small: block 0 -> Mv[k][o][i]; block 1 -> bias_all. grid = 2.
// ---------------------------------------------------------------------------
__global__ __launch_bounds__(256) void prep_small(const float* __restrict__ W_v,
                                                  const float* __restrict__ K_v,
                                                  const float* __restrict__ b_a,
                                                  const float* __restrict__ bk,
                                                  float* __restrict__ Mv,
                                                  float* __restrict__ bias_all) {
  const int tid = threadIdx.x;
  if (blockIdx.x == 0) {
    for (int idx = tid; idx < 2048; idx += 256) {
      const int k = idx >> 9, rem = idx & 511, o = rem >> 2, i = rem & 3;
      float acc = 0.f;
      for (int c = 0; c < 128; ++c)
        acc += K_v[(size_t)((o << 7) + c) * 4 + k] * W_v[(c << 2) + i];
      Mv[idx] = acc;   // layout [k][o][i]
    }
  } else {
    bias_all[tid] = b_a[tid] + bk[tid] + bk[256 + tid] + bk[512 + tid] + bk[768 + tid];
  }
}

// ---------------------------------------------------------------------------
// gemm_a (fused h): a_out[n,o] = sum_{tap,a} M[tap][o][a]*h[n+tap-2,a] + bias.
// Block: 128 nodes x 256 outs, 8 waves (2x4), wave = 64x64, mfma 16x16x32.
// h tile (131 rows x 256 ch, bf16, 528B stride) computed in-kernel into LDS.
// B (Ma) fragments loaded global->VGPR (L2-resident) -> NO barriers in K-loop.
// grid = 16*64, block = 512.
// ---------------------------------------------------------------------------
__global__ __launch_bounds__(512, 1) void gemm_a(const float* __restrict__ p0,
                                                 const float* __restrict__ p1,
                                                 const float* __restrict__ W1,
                                                 const float* __restrict__ b1,
                                                 const u16* __restrict__ Ma,
                                                 const float* __restrict__ bias_all,
                                                 float* __restrict__ out) {
  __shared__ __align__(16) char hs[131 * 528];   // 69,168 B
  __shared__ float nrm[131][4];
  const int tid = threadIdx.x;
  const int lane = tid & 63;
  const int wid = tid >> 6;
  const int wm = wid >> 2, wn = wid & 3;
  const int b = blockIdx.x >> 6;
  const int n0 = (blockIdx.x & 63) * 128;
  const int lhi = lane >> 4;   // 0..3
  const int llo = lane & 15;   // 0..15

  // --- per-thread W1/b1 registers: thread owns 8 consecutive a-cols ---
  const int g8 = tid & 31;      // a-group (cols 8*g8 .. 8*g8+7)
  const int strip = tid >> 5;   // row strip 0..15
  float w1r[8][4], b1r[8];
  {
    const float4* W14 = (const float4*)W1;
#pragma unroll
    for (int j = 0; j < 8; ++j) {
      const float4 w = W14[g8 * 8 + j];
      w1r[j][0] = w.x; w1r[j][1] = w.y; w1r[j][2] = w.z; w1r[j][3] = w.w;
      b1r[j] = b1[g8 * 8 + j];
    }
  }

  // --- norms for rows 0..130 (edge e = n0 + rr - 2) ---
  const size_t pbase = (size_t)b * NN * 3;
  for (int idx = tid; idx < 524; idx += 512) {
    const int rr = idx >> 2, i = idx & 3;
    const int e = n0 + rr - 2;
    float v = 0.f;
    if (e >= 0 && e < EE) {
      const float* P0 = p0 + pbase;
      const float* P1 = p1 + pbase;
      const float* hi = (i == 0) ? P0 + (size_t)(e + 1) * 3
                      : (i == 1) ? P1 + (size_t)(e + 1) * 3
                      : (i == 2) ? P1 + (size_t)e * 3
                                 : P1 + (size_t)(e + 1) * 3;
      const float* lo = (i == 0) ? P0 + (size_t)e * 3
                      : (i == 1) ? P1 + (size_t)e * 3
                      : (i == 2) ? P0 + (size_t)(e + 1) * 3
                                 : P0 + (size_t)e * 3;
      const float dx = hi[0] - lo[0], dy = hi[1] - lo[1], dz = hi[2] - lo[2];
      v = sqrtf(dx * dx + dy * dy + dz * dz);
    }
    nrm[rr][i] = v;
  }
  __syncthreads();

  // --- h tile: h[rr][a] = LeakyReLU(b1 + nrm . W1) as bf16, zero for pad rows
  for (int rr = strip; rr < 131; rr += 16) {
    const int e = n0 + rr - 2;
    const bool valid = (e >= 0) && (e < EE);
    const float nA = nrm[rr][0], nB = nrm[rr][1], nC = nrm[rr][2], nD = nrm[rr][3];
    u16x8 pack;
#pragma unroll
    for (int j = 0; j < 8; ++j) {
      float v = b1r[j] + nA * w1r[j][0] + nB * w1r[j][1] +
                nC * w1r[j][2] + nD * w1r[j][3];
      v = (v >= 0.f) ? v : 0.2f * v;
      pack[j] = valid ? f2bf(v) : (u16)0;
    }
    *(u16x8*)(hs + rr * 528 + g8 * 16) = pack;
  }
  __syncthreads();

  // --- barrier-free K-loop: q = tap*4 + ac, ks = half-chunk of 32 ---
  const f32x4 zero = {0.f, 0.f, 0.f, 0.f};
  f32x4 acc[4][4];
#pragma unroll
  for (int m = 0; m < 4; ++m)
#pragma unroll
    for (int nf = 0; nf < 4; ++nf) acc[m][nf] = zero;

  const char* mb = (const char*)Ma;
  for (int q = 0; q < 16; ++q) {
    const int tap = q >> 2;
    const int acB = (q & 3) * 128;   // byte offset of a-chunk within h row
#pragma unroll
    for (int ks = 0; ks < 2; ++ks) {
      const char* bptr = mb + (size_t)q * 36864 + ks * 64 + lhi * 16;
      bf16x8 bfr[4];
#pragma unroll
      for (int nf = 0; nf < 4; ++nf)
        bfr[nf] = *(const bf16x8*)(bptr + (wn * 64 + nf * 16 + llo) * 144);
      bf16x8 af[4];
      const int cA = acB + ks * 64 + lhi * 16;
#pragma unroll
      for (int m = 0; m < 4; ++m)
        af[m] = *(const bf16x8*)(hs + (wm * 64 + m * 16 + llo + tap) * 528 + cA);
#pragma unroll
      for (int m = 0; m < 4; ++m)
#pragma unroll
        for (int nf = 0; nf < 4; ++nf)
          acc[m][nf] = __builtin_amdgcn_mfma_f32_16x16x32_bf16(bfr[nf], af[m],
                                                               acc[m][nf], 0, 0, 0);
    }
  }

  // --- epilogue: D row = o (lhi*4+j), col = node (llo) -> float4 stores ---
#pragma unroll
  for (int m = 0; m < 4; ++m) {
    const int node = n0 + wm * 64 + m * 16 + llo;
    float* orow = out + ((size_t)b * NN + node) * AD;
#pragma unroll
    for (int nf = 0; nf < 4; ++nf) {
      const int o0 = wn * 64 + nf * 16 + lhi * 4;
      const float4 bias4 = *(const float4*)(bias_all + o0);
      float4 st;
      st.x = acc[m][nf][0] + bias4.x;
      st.y = acc[m][nf][1] + bias4.y;
      st.z = acc[m][nf][2] + bias4.z;
      st.w = acc[m][nf][3] + bias4.w;
      *(float4*)(orow + o0) = st;
    }
  }
}

// ---------------------------------------------------------------------------
// fixup_a: remove bias of conv taps that fall outside the edge range.
// ---------------------------------------------------------------------------
__global__ void fixup_a(const float* __restrict__ bk, float* __restrict__ out) {
  const int o = threadIdx.x;
  const int b = blockIdx.x;
  float* base = out + (size_t)b * NN * AD;
  base[o] -= bk[o] + bk[256 + o];
  base[AD + o] -= bk[o];
  base[(size_t)8190 * AD + o] -= bk[768 + o];
  base[(size_t)8191 * AD + o] -= bk[512 + o] + bk[768 + o];
}

// ---------------------------------------------------------------------------
// vec_path: v_out[n,o,d] = sum_{k,i} Mv[k][o][i] * vec(e=n+k-2, i, d)
// ---------------------------------------------------------------------------
__global__ __launch_bounds__(256) void vec_path(const float* __restrict__ p0,
                                                const float* __restrict__ p1,
                                                const float* __restrict__ Mv,
                                                float* __restrict__ out) {
  __shared__ float MvS[2048];
  __shared__ __align__(16) float ob[32 * 384];
  const int tid = threadIdx.x;
  const int b = blockIdx.x >> 8;
  const int n0 = (blockIdx.x & 255) * 32;
  for (int idx = tid; idx < 2048; idx += 256) MvS[idx] = Mv[idx];
  __syncthreads();
  const int nl = tid >> 3, q = tid & 7;
  const int n = n0 + nl;
  const size_t pbase = (size_t)b * NN * 3;
  float s[4][4][3];
#pragma unroll
  for (int k = 0; k < 4; ++k) {
    const int e = n + k - 2;
    if (e >= 0 && e < EE) {
      const float* A0 = p0 + pbase + (size_t)e * 3;
      const float* A1 = p0 + pbase + (size_t)(e + 1) * 3;
      const float* C0 = p1 + pbase + (size_t)e * 3;
      const float* C1 = p1 + pbase + (size_t)(e + 1) * 3;
#pragma unroll
      for (int d = 0; d < 3; ++d) {
        const float a0v = A0[d], a1v = A1[d], c0v = C0[d], c1v = C1[d];
        s[k][0][d] = a1v - a0v;
        s[k][1][d] = c1v - c0v;
        s[k][2][d] = c0v - a1v;
        s[k][3][d] = c1v - a0v;
      }
    } else {
#pragma unroll
      for (int i2 = 0; i2 < 4; ++i2)
#pragma unroll
        for (int d = 0; d < 3; ++d) s[k][i2][d] = 0.f;
    }
  }
  for (int oi = 0; oi < 16; ++oi) {
    const int o = q * 16 + oi;
    float r0 = 0.f, r1 = 0.f, r2 = 0.f;
#pragma unroll
    for (int k = 0; k < 4; ++k) {
      const float* mp = &MvS[((k << 7) + o) << 2];
#pragma unroll
      for (int i2 = 0; i2 < 4; ++i2) {
        const float m = mp[i2];
        r0 += m * s[k][i2][0];
        r1 += m * s[k][i2][1];
        r2 += m * s[k][i2][2];
      }
    }
    ob[nl * 384 + o * 3 + 0] = r0;
    ob[nl * 384 + o * 3 + 1] = r1;
    ob[nl * 384 + o * 3 + 2] = r2;
  }
  __syncthreads();
  float4* dst = (float4*)(out + 33554432ULL + ((size_t)b * NN + n0) * 384);
  const float4* srcv = (const float4*)ob;
  for (int idx = tid; idx < 3072; idx += 256) dst[idx] = srcv[idx];
}

// ---------------------------------------------------------------------------
extern "C" void kernel_launch(void* const* d_in, const int* in_sizes, int n_in,
                              void* d_out, int out_size, void* d_ws, size_t ws_size,
                              hipStream_t stream) {
  const float* pos_0 = (const float*)d_in[0];
  const float* pos_1 = (const float*)d_in[1];
  const float* W_v = (const float*)d_in[2];
  const float* W1 = (const float*)d_in[3];
  const float* b1 = (const float*)d_in[4];
  const float* W2 = (const float*)d_in[5];
  const float* b2 = (const float*)d_in[6];
  const float* K_a = (const float*)d_in[7];
  const float* b_a = (const float*)d_in[8];
  const float* K_v = (const float*)d_in[9];
  float* out = (float*)d_out;
  char* ws = (char*)d_ws;

  const size_t MA_BYTES = (size_t)16 * 256 * 72 * 2;    // 589,824
  u16* Ma = (u16*)(ws);
  float* bk = (float*)(ws + MA_BYTES);
  float* bias_all = (float*)(ws + MA_BYTES + 4096);
  float* Mv = (float*)(ws + MA_BYTES + 4096 + 1024);

  prep_ma<<<dim3(256), dim3(256), 0, stream>>>(W2, b2, K_a, Ma, bk);
  prep_small<<<dim3(2), dim3(256), 0, stream>>>(W_v, K_v, b_a, bk, Mv, bias_all);
  gemm_a<<<dim3(1024), dim3(512), 0, stream>>>(pos_0, pos_1, W1, b1, Ma, bias_all, out);
  fixup_a<<<dim3(16), dim3(256), 0, stream>>>(bk, out);
  vec_path<<<dim3(4096), dim3(256), 0, stream>>>(pos_0, pos_1, Mv, out);
}

// Round 3
// 217.669 us; speedup vs baseline: 1.4213x; 1.1921x over previous
//
#include <hip/hip_runtime.h>
#include <stdint.h>

#define NN 8192      // nodes per batch
#define EE 8191      // edges per batch
#define AD 256       // ADIM
#define BB 16        // batch

typedef unsigned short u16;
typedef short bf16x8 __attribute__((ext_vector_type(8)));
typedef float f32x4 __attribute__((ext_vector_type(4)));
typedef u16 u16x8 __attribute__((ext_vector_type(8)));

__device__ __forceinline__ u16 f2bf(float f) {
  unsigned u = __builtin_bit_cast(unsigned, f);
  u = u + 0x7fffu + ((u >> 16) & 1u);   // RNE
  return (u16)(u >> 16);
}

// ---------------------------------------------------------------------------
// prep_ma (merged): per block o:
//   Ma[s=tap*8+ac*2+ks][o][32] = bf16(sum_c K_a[o,c,tap] * W2[c, a]),
//     a = ac*64 + ks*32 + jj   (contiguous 64B rows -> coalesced gemm loads)
//   bk[tap][o] = sum_c K_a[o,c,tap]*b2[c];  bias_all[o] = b_a[o] + sum_t bk
//   blocks 0..7 additionally: Mv[k][o][i] = sum_c K_v[o,c,k]*W_v[c,i]
// grid = 256, block = 256.
// ---------------------------------------------------------------------------
__global__ __launch_bounds__(256) void prep_ma(const float* __restrict__ W2,
                                               const float* __restrict__ b2,
                                               const float* __restrict__ K_a,
                                               const float* __restrict__ b_a,
                                               const float* __restrict__ W_v,
                                               const float* __restrict__ K_v,
                                               u16* __restrict__ Ma,
                                               float* __restrict__ bk,
                                               float* __restrict__ bias_all,
                                               float* __restrict__ Mv) {
  __shared__ float ka[256][4];
  __shared__ float b2s[256];
  __shared__ float red[4];
  const int tid = threadIdx.x;
  const int o = blockIdx.x;
  const float4 kv = ((const float4*)K_a)[(size_t)o * 256 + tid];
  ka[tid][0] = kv.x; ka[tid][1] = kv.y; ka[tid][2] = kv.z; ka[tid][3] = kv.w;
  b2s[tid] = b2[tid];
  __syncthreads();
  float acc[4] = {0.f, 0.f, 0.f, 0.f};
  for (int c = 0; c < 256; ++c) {
    const float w = W2[(c << 8) + tid];
    acc[0] += ka[c][0] * w; acc[1] += ka[c][1] * w;
    acc[2] += ka[c][2] * w; acc[3] += ka[c][3] * w;
  }
  const int ac = tid >> 6, ks = (tid >> 5) & 1, jj = tid & 31;
#pragma unroll
  for (int t = 0; t < 4; ++t)
    Ma[((size_t)((t * 8 + ac * 2 + ks) * 256 + o)) * 32 + jj] = f2bf(acc[t]);
  if (tid < 4) {
    float s = 0.f;
    for (int c = 0; c < 256; ++c) s += ka[c][tid] * b2s[c];
    bk[tid * 256 + o] = s;
    red[tid] = s;
  }
  __syncthreads();
  if (tid == 0) bias_all[o] = b_a[o] + red[0] + red[1] + red[2] + red[3];
  if (blockIdx.x < 8) {
    const int idx2 = blockIdx.x * 256 + tid;   // 2048 entries: [k][ov][i]
    const int k = idx2 >> 9, rem = idx2 & 511, ov = rem >> 2, i = rem & 3;
    float a2 = 0.f;
    for (int c = 0; c < 128; ++c)
      a2 += K_v[(size_t)((ov << 7) + c) * 4 + k] * W_v[(c << 2) + i];
    Mv[idx2] = a2;
  }
}

// ---------------------------------------------------------------------------
// gemm_a (fused h + fixup): a_out[n,o] = sum M[tap][o][a]*h[n+tap-2,a] + bias.
// Block: 128 nodes x 256 outs, 8 waves (2x4), wave = 64x64, mfma 16x16x32.
// h tile computed in-kernel into LDS (131 x 528B). B streamed global->VGPR
// from contiguous [s][o][64B] layout; no barriers in K-loop.
// __launch_bounds__(512,4) caps VGPR at 128 -> 2 blocks/CU.
// grid = 16*64, block = 512.
// ---------------------------------------------------------------------------
__global__ __launch_bounds__(512, 4) void gemm_a(const float* __restrict__ p0,
                                                 const float* __restrict__ p1,
                                                 const float* __restrict__ W1,
                                                 const float* __restrict__ b1,
                                                 const u16* __restrict__ Ma,
                                                 const float* __restrict__ bias_all,
                                                 const float* __restrict__ bk,
                                                 float* __restrict__ out) {
  __shared__ __align__(16) char hs[131 * 528];   // 69,168 B
  __shared__ float nrm[131][4];
  const int tid = threadIdx.x;
  const int lane = tid & 63;
  const int wid = tid >> 6;
  const int wm = wid >> 2, wn = wid & 3;
  const int b = blockIdx.x >> 6;
  const int n0 = (blockIdx.x & 63) * 128;
  const int lhi = lane >> 4;   // 0..3
  const int llo = lane & 15;   // 0..15

  // --- norms for rows 0..130 (edge e = n0 + rr - 2) ---
  const size_t pbase = (size_t)b * NN * 3;
  for (int idx = tid; idx < 524; idx += 512) {
    const int rr = idx >> 2, i = idx & 3;
    const int e = n0 + rr - 2;
    float v = 0.f;
    if (e >= 0 && e < EE) {
      const float* P0 = p0 + pbase;
      const float* P1 = p1 + pbase;
      const float* hi = (i == 0) ? P0 + (size_t)(e + 1) * 3
                      : (i == 1) ? P1 + (size_t)(e + 1) * 3
                      : (i == 2) ? P1 + (size_t)e * 3
                                 : P1 + (size_t)(e + 1) * 3;
      const float* lo = (i == 0) ? P0 + (size_t)e * 3
                      : (i == 1) ? P1 + (size_t)e * 3
                      : (i == 2) ? P0 + (size_t)(e + 1) * 3
                                 : P0 + (size_t)e * 3;
      const float dx = hi[0] - lo[0], dy = hi[1] - lo[1], dz = hi[2] - lo[2];
      v = sqrtf(dx * dx + dy * dy + dz * dz);
    }
    nrm[rr][i] = v;
  }
  __syncthreads();

  // --- h tile: h[rr][a] = LeakyReLU(b1 + nrm . W1) as bf16, zero pad rows ---
  {
    const int g8 = tid & 31;      // a-group (cols 8*g8 .. 8*g8+7)
    const int strip = tid >> 5;   // row strip 0..15
    float w1r[8][4], b1r[8];
    const float4* W14 = (const float4*)W1;
#pragma unroll
    for (int j = 0; j < 8; ++j) {
      const float4 w = W14[g8 * 8 + j];
      w1r[j][0] = w.x; w1r[j][1] = w.y; w1r[j][2] = w.z; w1r[j][3] = w.w;
      b1r[j] = b1[g8 * 8 + j];
    }
    for (int rr = strip; rr < 131; rr += 16) {
      const int e = n0 + rr - 2;
      const bool valid = (e >= 0) && (e < EE);
      const float nA = nrm[rr][0], nB = nrm[rr][1], nC = nrm[rr][2], nD = nrm[rr][3];
      u16x8 pack;
#pragma unroll
      for (int j = 0; j < 8; ++j) {
        float v = b1r[j] + nA * w1r[j][0] + nB * w1r[j][1] +
                  nC * w1r[j][2] + nD * w1r[j][3];
        v = (v >= 0.f) ? v : 0.2f * v;
        pack[j] = valid ? f2bf(v) : (u16)0;
      }
      *(u16x8*)(hs + rr * 528 + g8 * 16) = pack;
    }
  }
  __syncthreads();

  // --- barrier-free K-loop: 32 steps, s = tap*8 + ac*2 + ks ---
  const f32x4 zero = {0.f, 0.f, 0.f, 0.f};
  f32x4 acc[4][4];
#pragma unroll
  for (int m = 0; m < 4; ++m)
#pragma unroll
    for (int nf = 0; nf < 4; ++nf) acc[m][nf] = zero;

  const char* mb = (const char*)Ma + (size_t)(wn * 64 + llo) * 64 + lhi * 16;
#pragma unroll
  for (int s = 0; s < 32; ++s) {
    const int tap = s >> 3;
    const int cA = ((s >> 1) & 3) * 128 + (s & 1) * 64 + lhi * 16;
    const char* bptr = mb + (size_t)s * 16384;
    bf16x8 bfr[4];
#pragma unroll
    for (int nf = 0; nf < 4; ++nf)
      bfr[nf] = *(const bf16x8*)(bptr + nf * 1024);
    bf16x8 af[4];
#pragma unroll
    for (int m = 0; m < 4; ++m)
      af[m] = *(const bf16x8*)(hs + (wm * 64 + m * 16 + llo + tap) * 528 + cA);
#pragma unroll
    for (int nf = 0; nf < 4; ++nf)
#pragma unroll
      for (int m = 0; m < 4; ++m)
        acc[m][nf] = __builtin_amdgcn_mfma_f32_16x16x32_bf16(bfr[nf], af[m],
                                                             acc[m][nf], 0, 0, 0);
  }

  // --- epilogue: D row = o (lhi*4+j), col = node (llo); fixup folded ---
#pragma unroll
  for (int m = 0; m < 4; ++m) {
    const int node = n0 + wm * 64 + m * 16 + llo;
    float* orow = out + ((size_t)b * NN + node) * AD;
    const bool edge = (node <= 1) | (node >= NN - 2);
#pragma unroll
    for (int nf = 0; nf < 4; ++nf) {
      const int o0 = wn * 64 + nf * 16 + lhi * 4;
      float bx = bias_all[o0], by = bias_all[o0 + 1],
            bz = bias_all[o0 + 2], bw = bias_all[o0 + 3];
      if (edge) {
        const float* k0 = bk + o0;
        const float* k1 = bk + 256 + o0;
        const float* k2 = bk + 512 + o0;
        const float* k3 = bk + 768 + o0;
        if (node == 0) {
          bx -= k0[0] + k1[0]; by -= k0[1] + k1[1];
          bz -= k0[2] + k1[2]; bw -= k0[3] + k1[3];
        } else if (node == 1) {
          bx -= k0[0]; by -= k0[1]; bz -= k0[2]; bw -= k0[3];
        } else if (node == NN - 2) {
          bx -= k3[0]; by -= k3[1]; bz -= k3[2]; bw -= k3[3];
        } else {
          bx -= k2[0] + k3[0]; by -= k2[1] + k3[1];
          bz -= k2[2] + k3[2]; bw -= k2[3] + k3[3];
        }
      }
      float4 st;
      st.x = acc[m][nf][0] + bx;
      st.y = acc[m][nf][1] + by;
      st.z = acc[m][nf][2] + bz;
      st.w = acc[m][nf][3] + bw;
      *(float4*)(orow + o0) = st;
    }
  }
}

// ---------------------------------------------------------------------------
// vec_path: v_out[n,o,d] = sum_{k,i} Mv[k][o][i] * vec(e=n+k-2, i, d)
// ---------------------------------------------------------------------------
__global__ __launch_bounds__(256) void vec_path(const float* __restrict__ p0,
                                                const float* __restrict__ p1,
                                                const float* __restrict__ Mv,
                                                float* __restrict__ out) {
  __shared__ float MvS[2048];
  __shared__ __align__(16) float ob[32 * 384];
  const int tid = threadIdx.x;
  const int b = blockIdx.x >> 8;
  const int n0 = (blockIdx.x & 255) * 32;
  for (int idx = tid; idx < 2048; idx += 256) MvS[idx] = Mv[idx];
  __syncthreads();
  const int nl = tid >> 3, q = tid & 7;
  const int n = n0 + nl;
  const size_t pbase = (size_t)b * NN * 3;
  float s[4][4][3];
#pragma unroll
  for (int k = 0; k < 4; ++k) {
    const int e = n + k - 2;
    if (e >= 0 && e < EE) {
      const float* A0 = p0 + pbase + (size_t)e * 3;
      const float* A1 = p0 + pbase + (size_t)(e + 1) * 3;
      const float* C0 = p1 + pbase + (size_t)e * 3;
      const float* C1 = p1 + pbase + (size_t)(e + 1) * 3;
#pragma unroll
      for (int d = 0; d < 3; ++d) {
        const float a0v = A0[d], a1v = A1[d], c0v = C0[d], c1v = C1[d];
        s[k][0][d] = a1v - a0v;
        s[k][1][d] = c1v - c0v;
        s[k][2][d] = c0v - a1v;
        s[k][3][d] = c1v - a0v;
      }
    } else {
#pragma unroll
      for (int i2 = 0; i2 < 4; ++i2)
#pragma unroll
        for (int d = 0; d < 3; ++d) s[k][i2][d] = 0.f;
    }
  }
  for (int oi = 0; oi < 16; ++oi) {
    const int o = q * 16 + oi;
    float r0 = 0.f, r1 = 0.f, r2 = 0.f;
#pragma unroll
    for (int k = 0; k < 4; ++k) {
      const float* mp = &MvS[((k << 7) + o) << 2];
#pragma unroll
      for (int i2 = 0; i2 < 4; ++i2) {
        const float m = mp[i2];
        r0 += m * s[k][i2][0];
        r1 += m * s[k][i2][1];
        r2 += m * s[k][i2][2];
      }
    }
    ob[nl * 384 + o * 3 + 0] = r0;
    ob[nl * 384 + o * 3 + 1] = r1;
    ob[nl * 384 + o * 3 + 2] = r2;
  }
  __syncthreads();
  float4* dst = (float4*)(out + 33554432ULL + ((size_t)b * NN + n0) * 384);
  const float4* srcv = (const float4*)ob;
  for (int idx = tid; idx < 3072; idx += 256) dst[idx] = srcv[idx];
}

// ---------------------------------------------------------------------------
extern "C" void kernel_launch(void* const* d_in, const int* in_sizes, int n_in,
                              void* d_out, int out_size, void* d_ws, size_t ws_size,
                              hipStream_t stream) {
  const float* pos_0 = (const float*)d_in[0];
  const float* pos_1 = (const float*)d_in[1];
  const float* W_v = (const float*)d_in[2];
  const float* W1 = (const float*)d_in[3];
  const float* b1 = (const float*)d_in[4];
  const float* W2 = (const float*)d_in[5];
  const float* b2 = (const float*)d_in[6];
  const float* K_a = (const float*)d_in[7];
  const float* b_a = (const float*)d_in[8];
  const float* K_v = (const float*)d_in[9];
  float* out = (float*)d_out;
  char* ws = (char*)d_ws;

  const size_t MA_BYTES = (size_t)32 * 256 * 32 * 2;    // 524,288
  u16* Ma = (u16*)(ws);
  float* bk = (float*)(ws + MA_BYTES);
  float* bias_all = (float*)(ws + MA_BYTES + 4096);
  float* Mv = (float*)(ws + MA_BYTES + 4096 + 1024);

  prep_ma<<<dim3(256), dim3(256), 0, stream>>>(W2, b2, K_a, b_a, W_v, K_v,
                                               Ma, bk, bias_all, Mv);
  gemm_a<<<dim3(1024), dim3(512), 0, stream>>>(pos_0, pos_1, W1, b1, Ma,
                                               bias_all, bk, out);
  vec_path<<<dim3(4096), dim3(256), 0, stream>>>(pos_0, pos_1, Mv, out);
}